// Round 13
// baseline (135.433 us; speedup 1.0000x reference)
//
#include <hip/hip_runtime.h>

#define NB 2
#define LX 2048
#define LZ 2048
#define HH 16
#define DA 64
#define DM 64
#define HD 1024
#define KVS 2048              // fused K|V buffer row stride
#define MINF  -1000000.0f
#define QSC   0.1803368801f   // 0.125 * log2(e): softmax done in base-2 domain
#define DTHR  8.0f            // defer-max threshold (base-2): P <= 2^8

typedef __attribute__((ext_vector_type(8))) short short8;
typedef __attribute__((ext_vector_type(4))) float f32x4;

static __device__ __forceinline__ ushort f2bf(float f) {
    union { float f; uint32_t u; } c; c.f = f;
    return (ushort)((c.u + 0x7FFFu + ((c.u >> 16) & 1u)) >> 16);
}

static __device__ __forceinline__ float bf2f(ushort u) {
    union { uint32_t u; float f; } c; c.u = (uint32_t)u << 16;
    return c.f;
}

static __device__ __forceinline__ uint32_t cvtpk(float lo, float hi) {
    uint32_t r;
    asm("v_cvt_pk_bf16_f32 %0, %1, %2" : "=v"(r) : "v"(lo), "v"(hi));
    return r;
}

#define GL16(g, l) __builtin_amdgcn_global_load_lds( \
    (const __attribute__((address_space(1))) void*)(g), \
    (__attribute__((address_space(3))) void*)(l), 16, 0, 0)

// ---------------------------------------------------------------------------
// Fused preprocessing, one launch (11264 blocks):
//   [0,8192)      fp32->bf16 of both activations
//   [8192,9216)   4 weight transposes (f32 [K][N] -> bf16 [N][K])
//   [9216,11264)  mask tile classification (0 all-masked / 1 all-pass / 2 mix)
// ---------------------------------------------------------------------------
__global__ __launch_bounds__(256) void prep(
    const float* __restrict__ pA, const float* __restrict__ pB,
    ushort* __restrict__ oA, ushort* __restrict__ oB,
    const float* __restrict__ W0, const float* __restrict__ W1,
    const float* __restrict__ W2, const float* __restrict__ W3,
    ushort* __restrict__ T0, ushort* __restrict__ T1,
    ushort* __restrict__ T2, ushort* __restrict__ T3,
    const int* __restrict__ amask, const int* __restrict__ pmask,
    int* __restrict__ cls)
{
    const int fid = blockIdx.x;
    const int t = threadIdx.x;
    if (fid < 8192) {
        const int i = fid * 256 + t;
        const float* in = (i < 1048576) ? pA : pB;
        ushort* out = (i < 1048576) ? oA : oB;
        const int j = i & 1048575;
        float4 v = ((const float4*)in)[j];
        ushort4 o;
        o.x = f2bf(v.x); o.y = f2bf(v.y); o.z = f2bf(v.z); o.w = f2bf(v.w);
        ((ushort4*)out)[j] = o;
    } else if (fid < 9216) {
        __shared__ ushort Ls[64][72];
        const int id2 = fid - 8192;                 // 0..1023
        const int zz = id2 >> 8, rem = id2 & 255;
        const float* W = (zz == 0) ? W0 : (zz == 1) ? W1 : (zz == 2) ? W2 : W3;
        ushort* Wt = (zz == 0) ? T0 : (zz == 1) ? T1 : (zz == 2) ? T2 : T3;
        const int n0 = (rem & 15) * 64, k0 = (rem >> 4) * 64;
        const int rr = t >> 4, c4 = (t & 15) * 4;
        #pragma unroll
        for (int i = 0; i < 4; ++i) {
            const int r = rr + i * 16;
            float4 v = *(const float4*)&W[(size_t)(k0 + r) * 1024 + n0 + c4];
            Ls[c4 + 0][r] = f2bf(v.x);
            Ls[c4 + 1][r] = f2bf(v.y);
            Ls[c4 + 2][r] = f2bf(v.z);
            Ls[c4 + 3][r] = f2bf(v.w);
        }
        __syncthreads();
        const int n = t >> 2, kc = (t & 3) * 16;
        *(short8*)&Wt[(size_t)(n0 + n) * 1024 + k0 + kc]     = *(const short8*)&Ls[n][kc];
        *(short8*)&Wt[(size_t)(n0 + n) * 1024 + k0 + kc + 8] = *(const short8*)&Ls[n][kc + 8];
    } else {
        const int bid = fid - 9216;                 // 0..2047
        const int b = bid >> 10, xb = (bid >> 5) & 31, zb = bid & 31;
        int andv = 1, orv = 0;
        #pragma unroll
        for (int i = 0; i < 16; ++i) {
            const int e = t + i * 256;
            const int r = e >> 6, z = e & 63;
            const int m = amask[((size_t)b * LX + xb * 64 + r) * LZ + zb * 64 + z];
            const int p = pmask[(size_t)b * LZ + zb * 64 + z];
            const int v = (m != 0) & (p != 0);
            andv &= v; orv |= v;
        }
        __shared__ int sa[256];
        __shared__ int so[256];
        sa[t] = andv; so[t] = orv;
        __syncthreads();
        for (int s = 128; s > 0; s >>= 1) {
            if (t < s) { sa[t] &= sa[t + s]; so[t] |= so[t + s]; }
            __syncthreads();
        }
        if (t == 0) cls[bid] = so[0] ? (sa[0] ? 1 : 2) : 0;
    }
}

// ---------------------------------------------------------------------------
// Deep-pipelined QKV projection GEMM. 256x256 tile, BK=32, 512 thr (8 waves,
// 2x4), TRIPLE-buffered LDS (96 KB): iteration j computes K-step j from
// buf(j%3) while staging K-step j+2 into buf((j+2)%3) -- the freed buffer --
// so the boundary wait is a COUNTED `s_waitcnt vmcnt(4)` + raw s_barrier
// (never the compiler's vmcnt(0) drain; T3+T4, m218). BK=32 gives 64B LDS
// rows -> frag-read bank pattern (4*lr+lg)&7 is uniform (conflict-free, no
// swizzle needed). bid<64: Q = P @ WqT (x QSC); bid>=64: [K|V] = C @ WkvT,
// output stride 2048. T5 setprio around the 32-MFMA cluster.
// ---------------------------------------------------------------------------
__global__ __launch_bounds__(512, 2) void gemm_qkv256(
    const ushort* __restrict__ Pb, const ushort* __restrict__ Cb,
    const ushort* __restrict__ Wqt, const ushort* __restrict__ Wkvt,
    ushort* __restrict__ Qb, ushort* __restrict__ KV)
{
    __shared__ ushort lds[49152];   // 3 bufs x (A 8192 + B 8192) ushort

    const int bid = blockIdx.x;
    const bool isQ = bid < 64;
    const ushort* A  = isQ ? Pb : Cb;
    const ushort* Bt = isQ ? Wqt : Wkvt;
    ushort* Cout = isQ ? Qb : KV;
    const int ostr = isQ ? 1024 : KVS;
    const float osc = isQ ? QSC : 1.0f;
    int mt, nt;
    if (isQ) { mt = bid >> 2; nt = bid & 3; }
    else     { const int i2 = bid - 64; mt = i2 >> 3; nt = i2 & 7; }
    const int m0 = mt * 256, n0 = nt * 256;

    const int t = threadIdx.x;
    const int w = t >> 6, l = t & 63, lr = l & 15, lg = l >> 4;
    const int wm = w >> 2, wn = w & 3;

    // staging: chunk p = t + li*512 -> row p>>2, 16B chunk p&3 (linear)
    const int rA0 = t >> 2, cA0 = (t & 3) * 8;
    const int rA1 = (t + 512) >> 2, cA1 = ((t + 512) & 3) * 8;
    const ushort* srcA0 = &A[(size_t)(m0 + rA0) * 1024 + cA0];
    const ushort* srcA1 = &A[(size_t)(m0 + rA1) * 1024 + cA1];
    const ushort* srcB0 = &Bt[(size_t)(n0 + rA0) * 1024 + cA0];
    const ushort* srcB1 = &Bt[(size_t)(n0 + rA1) * 1024 + cA1];
    // LDS wave-uniform bases (ushort idx); HW appends lane*16B
    const int dA0 = (w * 64) * 8;
    const int dA1 = (w * 64 + 512) * 8;

    // frag read offsets (ushort idx, loop-invariant, statically indexed)
    int aoff[8], boff[4];
    #pragma unroll
    for (int mi = 0; mi < 8; ++mi) {
        const int row = wm * 128 + mi * 16 + lr;
        aoff[mi] = row * 32 + lg * 8;
    }
    #pragma unroll
    for (int nj = 0; nj < 4; ++nj) {
        const int row = wn * 64 + nj * 16 + lr;
        boff[nj] = 8192 + row * 32 + lg * 8;
    }

#define QSTAGE(kk, bufbase) do {                                   \
        const int k0s = (kk) * 32;                                 \
        GL16(srcA0 + k0s, &lds[(bufbase) + dA0]);                  \
        GL16(srcA1 + k0s, &lds[(bufbase) + dA1]);                  \
        GL16(srcB0 + k0s, &lds[(bufbase) + 8192 + dA0]);           \
        GL16(srcB1 + k0s, &lds[(bufbase) + 8192 + dA1]);           \
    } while (0)

    f32x4 acc[8][4];
    #pragma unroll
    for (int mi = 0; mi < 8; ++mi)
        #pragma unroll
        for (int nj = 0; nj < 4; ++nj) acc[mi][nj] = 0.f;

    int bcur = 0, bnxt = 16384, bnx2 = 32768;

    QSTAGE(0, bcur);
    QSTAGE(1, bnxt);
    asm volatile("s_waitcnt vmcnt(4)" ::: "memory");   // K-step 0 landed
    __builtin_amdgcn_s_barrier();
    __builtin_amdgcn_sched_barrier(0);

    for (int j = 0; j < 32; ++j) {
        // stage K-step j+2 into the buffer freed at the end of j-1.
        // j>=30 wraps (re-stages steps 0/1, never read) to keep the
        // vmcnt arithmetic uniform -- no tail conditionals.
        QSTAGE((j + 2) & 31, bnx2);

        short8 af[8], bf[4];
        #pragma unroll
        for (int mi = 0; mi < 8; ++mi)
            af[mi] = *(const short8*)&lds[bcur + aoff[mi]];
        #pragma unroll
        for (int nj = 0; nj < 4; ++nj)
            bf[nj] = *(const short8*)&lds[bcur + boff[nj]];

        __builtin_amdgcn_s_setprio(1);
        #pragma unroll
        for (int mi = 0; mi < 8; ++mi)
            #pragma unroll
            for (int nj = 0; nj < 4; ++nj)
                acc[mi][nj] = __builtin_amdgcn_mfma_f32_16x16x32_bf16(
                    af[mi], bf[nj], acc[mi][nj], 0, 0, 0);
        __builtin_amdgcn_s_setprio(0);

        // counted wait: FIFO retirement => <=4 outstanding means K-step j+1
        // (issued last iteration) has fully landed; j+2's 4 may stay in flight.
        asm volatile("s_waitcnt vmcnt(4)" ::: "memory");
        __builtin_amdgcn_s_barrier();
        __builtin_amdgcn_sched_barrier(0);

        const int tmp = bcur; bcur = bnxt; bnxt = bnx2; bnx2 = tmp;
    }
#undef QSTAGE

    const int row0 = m0 + wm * 128, col0 = n0 + wn * 64;
    #pragma unroll
    for (int mi = 0; mi < 8; ++mi)
        #pragma unroll
        for (int nj = 0; nj < 4; ++nj) {
            const int col = col0 + nj * 16 + lr;
            #pragma unroll
            for (int r = 0; r < 4; ++r) {
                const int row = row0 + mi * 16 + lg * 4 + r;
                Cout[(size_t)row * ostr + col] = f2bf(acc[mi][nj][r] * osc);
            }
        }
}

// ---------------------------------------------------------------------------
// MFMA flash attention (round-8 structure + balanced XCD clustering; round-12
// best measured). Split-KV x2, 64 q-rows/block, single K/V LDS buffer,
// 2 barriers/tile, 2048 blocks. K/V from fused KV buffer (stride 2048).
// Swapped QK^T; zero-shuffle PV (sigma z-order); defer-max; deferred
// l-reduction; setprio(1) on MFMA. Writes PARTIAL O (bf16) + (m,l) f32.
// ---------------------------------------------------------------------------
__global__ __launch_bounds__(256, 4) void attn_mfma(
    const ushort* __restrict__ Qg, const ushort* __restrict__ KVg,
    const int* __restrict__ amask, const int* __restrict__ pmask,
    const int* __restrict__ cls, ushort* __restrict__ Op,
    float2* __restrict__ ml)
{
    __shared__ ushort Ks[64 * 72];   // [z][d], pad 72
    __shared__ ushort Vt[64 * 64];   // [m][z], chunk-XOR swizzled

    const int t = threadIdx.x, w = t >> 6, l = t & 63, lr = l & 15, lg = l >> 4;
    const int flat = blockIdx.x + 32 * (blockIdx.y + 16 * blockIdx.z); // 0..2047
    const int xcd = flat & 7, ii = flat >> 3;       // ii 0..255
    const int g = xcd + 8 * (ii >> 5);              // 0..63
    const int xr_ = ii & 31;
    const int h = g & 15, bs = g >> 4;              // bs 0..3
    const int b = bs & 1, sKV = bs >> 1;
    const int fx = (xr_ & 1) ? 31 - (xr_ >> 1) : (xr_ >> 1);
    const int qb = b ? 31 - fx : fx;
    const int qw = qb * 64 + w * 16;

    short8 qf[2];
    #pragma unroll
    for (int ks = 0; ks < 2; ++ks)
        qf[ks] = *(const short8*)&Qg[(size_t)(b * LX + qw + lr) * HD
                                     + h * DA + ks * 32 + lg * 8];

    float mrun = -1e30f, lrun = 0.f;   // lrun = per-lane partial (16 slots)
    f32x4 o[4];
    #pragma unroll
    for (int mj = 0; mj < 4; ++mj) o[mj] = 0.f;

    const int kz = t >> 2, kc = (t & 3) * 16;      // K staging
    const int vz = (t >> 3) * 2, vc = (t & 7) * 8; // V staging (2 rows x 8 cols)

    for (int zb = sKV; zb < LZ / 64; zb += 2) {
        const int cl = cls[b * 1024 + qb * 32 + zb];   // uniform across block
        if (cl == 0) continue;
        const int z0 = zb * 64;

        __syncthreads();                // prior tile's LDS reads done
        {
            const ushort* kp = &KVg[(size_t)(b * LZ + z0 + kz) * KVS + h * DA + kc];
            *(short8*)&Ks[kz * 72 + kc]     = *(const short8*)kp;
            *(short8*)&Ks[kz * 72 + kc + 8] = *(const short8*)(kp + 8);
            const ushort* vp = &KVg[(size_t)(b * LZ + z0 + vz) * KVS + 1024 + h * DM + vc];
            short8 v0 = *(const short8*)vp;
            short8 v1 = *(const short8*)(vp + KVS);
            const int zc = vz >> 3, zo = vz & 7;
            #pragma unroll
            for (int j = 0; j < 8; ++j) {
                const int m = vc + j;
                const int idx = m * 64 + (((zc ^ m ^ (m >> 3)) & 7) << 3) + zo;
                *(uint32_t*)&Vt[idx] =
                    (uint32_t)(ushort)v0[j] | ((uint32_t)(ushort)v1[j] << 16);
            }
        }
        __syncthreads();

        // ---- S^T = K @ Q : lane holds S[q=lr][z = nj*16 + lg*4 + r] ----
        f32x4 s[4];
        __builtin_amdgcn_s_setprio(1);
        #pragma unroll
        for (int nj = 0; nj < 4; ++nj) {
            const short8 kf0 = *(const short8*)&Ks[(nj * 16 + lr) * 72 + lg * 8];
            const short8 kf1 = *(const short8*)&Ks[(nj * 16 + lr) * 72 + 32 + lg * 8];
            f32x4 z4 = 0.f;
            z4 = __builtin_amdgcn_mfma_f32_16x16x32_bf16(kf0, qf[0], z4, 0, 0, 0);
            z4 = __builtin_amdgcn_mfma_f32_16x16x32_bf16(kf1, qf[1], z4, 0, 0, 0);
            s[nj] = z4;
        }
        __builtin_amdgcn_s_setprio(0);
        // ---- mask (mixed tiles only) ----
        if (cl == 2) {
            const size_t arow = (size_t)(b * LX + qw + lr) * LZ + z0;
            #pragma unroll
            for (int nj = 0; nj < 4; ++nj)
                #pragma unroll
                for (int r = 0; r < 4; ++r) {
                    const int z = nj * 16 + lg * 4 + r;
                    const int ok = (amask[arow + z] != 0) & (pmask[b * LZ + z0 + z] != 0);
                    if (!ok) s[nj][r] = MINF;
                }
        }
        // ---- online softmax, base-2, defer-max (row stats live at q=lr) ----
        {
            float pm = s[0][0];
            #pragma unroll
            for (int nj = 0; nj < 4; ++nj)
                #pragma unroll
                for (int r = 0; r < 4; ++r) pm = fmaxf(pm, s[nj][r]);
            pm = fmaxf(pm, __shfl_xor(pm, 16));
            pm = fmaxf(pm, __shfl_xor(pm, 32));
            if (__any(pm > mrun + DTHR)) {
                const float mn = fmaxf(mrun, pm);
                const float al = exp2f(mrun - mn);
                mrun = mn;
                lrun *= al;
                #pragma unroll
                for (int r = 0; r < 4; ++r) {
                    const float alq = __shfl(al, (lg << 2) + r);
                    #pragma unroll
                    for (int mj = 0; mj < 4; ++mj) o[mj][r] *= alq;
                }
            }
            #pragma unroll
            for (int nj = 0; nj < 4; ++nj)
                #pragma unroll
                for (int r = 0; r < 4; ++r) {
                    const float p = exp2f(s[nj][r] - mrun);
                    s[nj][r] = p;
                    lrun += p;     // per-lane partial; cross-lane reduce at end
                }
        }
        // ---- P -> PV A-frags: pack own registers (sigma z-order) ----
        short8 pa[2];
        {
            uint32_t pk01[4], pk23[4];
            #pragma unroll
            for (int nj = 0; nj < 4; ++nj) {
                pk01[nj] = cvtpk(s[nj][0], s[nj][1]);
                pk23[nj] = cvtpk(s[nj][2], s[nj][3]);
            }
            #pragma unroll
            for (int ks = 0; ks < 2; ++ks) {
                union { uint32_t d[4]; short8 v; } u;
                u.d[0] = pk01[2 * ks];
                u.d[1] = pk23[2 * ks];
                u.d[2] = pk01[2 * ks + 1];
                u.d[3] = pk23[2 * ks + 1];
                pa[ks] = u.v;
            }
        }
        // ---- O += P @ V (V-frags in matching sigma z-order, 4x b64 each) ----
        __builtin_amdgcn_s_setprio(1);
        #pragma unroll
        for (int mj = 0; mj < 4; ++mj) {
            const int m_ = mj * 16 + lr;
            const int xr = (m_ ^ (m_ >> 3)) & 7;
            const int czb = lg >> 1;
            const int zo = (lg & 1) * 4;
            #pragma unroll
            for (int ks = 0; ks < 2; ++ks) {
                const int clo = (ks * 4 + czb) ^ xr;
                const int chi = (ks * 4 + 2 + czb) ^ xr;
                const uint2 lo = *(const uint2*)&Vt[m_ * 64 + ((clo & 7) << 3) + zo];
                const uint2 hi = *(const uint2*)&Vt[m_ * 64 + ((chi & 7) << 3) + zo];
                union { uint32_t d[4]; short8 v; } u;
                u.d[0] = lo.x; u.d[1] = lo.y; u.d[2] = hi.x; u.d[3] = hi.y;
                o[mj] = __builtin_amdgcn_mfma_f32_16x16x32_bf16(pa[ks], u.v, o[mj], 0, 0, 0);
            }
        }
        __builtin_amdgcn_s_setprio(0);
    }

    // ---- epilogue: finish l reduction, store partials (no normalize) ----
    lrun += __shfl_xor(lrun, 16);
    lrun += __shfl_xor(lrun, 32);
    if (l < 16)
        ml[(size_t)((sKV * NB + b) * HH + h) * LX + qw + l] = make_float2(mrun, lrun);
    const size_t ob = (size_t)((sKV * NB + b) * LX + qw) * HD + h * DM;
    #pragma unroll
    for (int r = 0; r < 4; ++r)
        #pragma unroll
        for (int mj = 0; mj < 4; ++mj)
            Op[ob + (size_t)((lg << 2) + r) * HD + mj * 16 + lr] = f2bf(o[mj][r]);
}

// ---------------------------------------------------------------------------
// Output GEMM with fused split-KV combine AND in-kernel combine weights.
// Tile 64x128, BK=32, 4 waves; fp32 out + bias.
// ---------------------------------------------------------------------------
__global__ __launch_bounds__(256) void gemm_out_fused(
    const ushort* __restrict__ Op, const float2* __restrict__ ml,
    const ushort* __restrict__ Bt, const float* __restrict__ bias,
    float* __restrict__ Cout)
{
    __shared__ ushort As[64 * 32];
    __shared__ ushort Bs[128 * 32];
    __shared__ float2 Wl[64][17];
    const int t = threadIdx.x;
    const int w = t >> 6, l = t & 63, lr = l & 15, lg = l >> 4;
    const int wr = w >> 1, wc = w & 1;
    const int n0 = blockIdx.x * 128, m0 = blockIdx.y * 64;

    {
        const int e = t * 4;
        #pragma unroll
        for (int j = 0; j < 4; ++j) {
            const int rl = (e + j) >> 4, hh = (e + j) & 15;
            const int ra = m0 + rl;
            const int bb = ra >> 11, xx = ra & 2047;
            const float2 a0 = ml[(size_t)(bb * HH + hh) * LX + xx];
            const float2 a1 = ml[(size_t)((NB + bb) * HH + hh) * LX + xx];
            const float M = fmaxf(a0.x, a1.x);
            const float w0 = exp2f(a0.x - M), w1 = exp2f(a1.x - M);
            const float inv = 1.f / fmaxf(a0.y * w0 + a1.y * w1, 1e-37f);
            Wl[rl][hh] = make_float2(w0 * inv, w1 * inv);
        }
    }
    __syncthreads();

    const int ra = m0 + (t >> 2), ka = (t & 3) * 8;
    const ushort* p0 = &Op[(size_t)ra * HD + ka];
    const ushort* p1 = p0 + (size_t)NB * LX * HD;
    const ushort* b0 = &Bt[(size_t)(n0 + (t >> 2)) * 1024 + ka];
    const ushort* b1 = &Bt[(size_t)(n0 + 64 + (t >> 2)) * 1024 + ka];
    ushort* lB0 = &Bs[w * 512];
    ushort* lB1 = &Bs[(4 + w) * 512];

    f32x4 acc[2][4];
    #pragma unroll
    for (int i = 0; i < 2; ++i)
        #pragma unroll
        for (int j = 0; j < 4; ++j) acc[i][j] = 0.f;

    for (int k0 = 0; k0 < 1024; k0 += 32) {
        const short8 q0 = *(const short8*)(p0 + k0);
        const short8 q1 = *(const short8*)(p1 + k0);
        const float2 wv = Wl[t >> 2][(k0 + ka) >> 6];
        union { ushort d[8]; short8 v; } av;
        #pragma unroll
        for (int j = 0; j < 8; ++j)
            av.d[j] = f2bf(bf2f((ushort)q0[j]) * wv.x + bf2f((ushort)q1[j]) * wv.y);
        __syncthreads();
        *(short8*)&As[t * 8] = av.v;
        GL16(b0 + k0, lB0);
        GL16(b1 + k0, lB1);
        __syncthreads();
        short8 af[2], bf[4];
        #pragma unroll
        for (int mi = 0; mi < 2; ++mi)
            af[mi] = *(const short8*)&As[(wr * 32 + mi * 16 + lr) * 32 + lg * 8];
        #pragma unroll
        for (int nj = 0; nj < 4; ++nj)
            bf[nj] = *(const short8*)&Bs[(wc * 64 + nj * 16 + lr) * 32 + lg * 8];
        #pragma unroll
        for (int mi = 0; mi < 2; ++mi)
            #pragma unroll
            for (int nj = 0; nj < 4; ++nj)
                acc[mi][nj] = __builtin_amdgcn_mfma_f32_16x16x32_bf16(
                    af[mi], bf[nj], acc[mi][nj], 0, 0, 0);
    }

    const int row0 = m0 + wr * 32, col0 = n0 + wc * 64;
    #pragma unroll
    for (int mi = 0; mi < 2; ++mi)
        #pragma unroll
        for (int nj = 0; nj < 4; ++nj) {
            const int col = col0 + nj * 16 + lr;
            #pragma unroll
            for (int r = 0; r < 4; ++r) {
                const int row = row0 + mi * 16 + lg * 4 + r;
                Cout[(size_t)row * 1024 + col] = acc[mi][nj][r] + bias[col];
            }
        }
}

// ---------------------------------------------------------------------------
extern "C" void kernel_launch(void* const* d_in, const int* in_sizes, int n_in,
                              void* d_out, int out_size, void* d_ws, size_t ws_size,
                              hipStream_t stream)
{
    const float* primary = (const float*)d_in[0];
    const float* context = (const float*)d_in[1];
    const int*   pmask   = (const int*)d_in[2];
    const int*   amask   = (const int*)d_in[3];
    const float* Wq      = (const float*)d_in[4];
    const float* Wk      = (const float*)d_in[5];
    const float* Wv      = (const float*)d_in[6];
    const float* Wo      = (const float*)d_in[7];
    const float* bo      = (const float*)d_in[8];
    float* out = (float*)d_out;

    char* w8 = (char*)d_ws;
    ushort* Pb  = (ushort*)(w8 + 0);          // dead after gemm_qkv -> Op alias
    ushort* Cb  = (ushort*)(w8 + 8388608);
    ushort* Qb  = (ushort*)(w8 + 16777216);
    ushort* KV  = (ushort*)(w8 + 25165824);   // [4096][2048] bf16 = 16 MB
    ushort* Wqt = (ushort*)(w8 + 50331648);   // dead after gemm_qkv -> ml alias
    ushort* Wkt = (ushort*)(w8 + 52428800);   // [WkT;WvT] fused 2048x1024
    ushort* Wvt = (ushort*)(w8 + 54525952);
    ushort* Wot = (ushort*)(w8 + 56623104);
    int*    clsp = (int*)(w8 + 58720256);
    ushort* Op   = Pb;                        // 2 x 8.4 MB partials (Pb+Cb)
    float2* mlp  = (float2*)Wqt;              // 1 MB

    prep<<<11264, 256, 0, stream>>>(primary, context, Pb, Cb,
                                    Wq, Wk, Wv, Wo, Wqt, Wkt, Wvt, Wot,
                                    amask, pmask, clsp);
    gemm_qkv256<<<192, 512, 0, stream>>>(Pb, Cb, Wqt, Wkt, Qb, KV);
    attn_mfma<<<dim3(32, 16, 4), 256, 0, stream>>>(Qb, KV, amask, pmask, clsp, Op, mlp);
    gemm_out_fused<<<dim3(8, 64), 256, 0, stream>>>(Op, mlp, Wot, bo, out);
}